// Round 7
// baseline (147.042 us; speedup 1.0000x reference)
//
#include <hip/hip_runtime.h>
#include <stdint.h>

#define D_MODEL 1024
#define NHEADS  16
#define DEPTH   64
#define BATCH   2
#define SEQ     2048
#define M_TOK   (BATCH*SEQ)   // 4096

typedef __attribute__((ext_vector_type(8)))  short short8;
typedef __attribute__((ext_vector_type(4)))  float f32x4;
typedef __attribute__((ext_vector_type(16))) float f32x16;
typedef __attribute__((ext_vector_type(4)))  unsigned int uint4v;

__device__ __forceinline__ unsigned short f2bf(float f) {
  unsigned int u = __float_as_uint(f);
  u += 0x7fffu + ((u >> 16) & 1u);
  return (unsigned short)(u >> 16);
}

__device__ __forceinline__ unsigned int cvt_pk_bf16(float lo, float hi) {
  unsigned int r;
  asm("v_cvt_pk_bf16_f32 %0, %1, %2" : "=v"(r) : "v"(lo), "v"(hi));
  return r;
}

__device__ __forceinline__ void gload_lds16(const unsigned short* g, unsigned short* l) {
  __builtin_amdgcn_global_load_lds((const __attribute__((address_space(1))) void*)g,
                                   (__attribute__((address_space(3))) void*)l, 16, 0, 0);
}

// ---------------- fp32 -> bf16 elementwise (x) ----------------
__global__ void mha_cvt_bf16(const float* __restrict__ in, unsigned short* __restrict__ out) {
  int i = (blockIdx.x * 256 + threadIdx.x) * 8;
  float4 a = *(const float4*)(in + i);
  float4 b = *(const float4*)(in + i + 4);
  uint4 r;
  r.x = (unsigned)f2bf(a.x) | ((unsigned)f2bf(a.y) << 16);
  r.y = (unsigned)f2bf(a.z) | ((unsigned)f2bf(a.w) << 16);
  r.z = (unsigned)f2bf(b.x) | ((unsigned)f2bf(b.y) << 16);
  r.w = (unsigned)f2bf(b.z) | ((unsigned)f2bf(b.w) << 16);
  *(uint4*)(out + i) = r;
}

// ------- Wqkv [1024][3072] -> permuted transposed bf16 --------
__global__ void mha_perm_wqkv(const float* __restrict__ W,
                              unsigned short* __restrict__ wqkT,
                              unsigned short* __restrict__ wvT) {
  __shared__ float tile[32][33];
  int c0 = blockIdx.x * 32, k0 = blockIdx.y * 32;
  int tx = threadIdx.x, ty = threadIdx.y;
  for (int i = ty; i < 32; i += 8)
    tile[i][tx] = W[(size_t)(k0 + i) * 3072 + c0 + tx];
  __syncthreads();
  for (int i = ty; i < 32; i += 8) {
    int c = c0 + i;
    int hd = c / 3;
    int s = c - hd * 3;
    unsigned short v = f2bf(tile[tx][i]);
    if (s < 2) wqkT[(size_t)(s * 1024 + hd) * 1024 + k0 + tx] = v;
    else       wvT [(size_t)hd * 1024 + k0 + tx] = v;
  }
}

// ------- Wproj [1024][1024] -> transposed bf16 [c][k] --------
__global__ void mha_t_wproj(const float* __restrict__ W, unsigned short* __restrict__ wpT) {
  __shared__ float tile[32][33];
  int c0 = blockIdx.x * 32, k0 = blockIdx.y * 32;
  int tx = threadIdx.x, ty = threadIdx.y;
  for (int i = ty; i < 32; i += 8)
    tile[i][tx] = W[(size_t)(k0 + i) * 1024 + c0 + tx];
  __syncthreads();
  for (int i = ty; i < 32; i += 8)
    wpT[(size_t)(c0 + i) * 1024 + k0 + tx] = f2bf(tile[tx][i]);
}

// ---------------- 128x128 bf16 gemm_bt (m97-style) ----------------
template<int MODE>
__global__ __launch_bounds__(256, 2) void mha_gemm_bt(
    const unsigned short* __restrict__ A,
    const unsigned short* __restrict__ Bt,
    const float* __restrict__ bias,
    unsigned short* __restrict__ out_a,
    unsigned short* __restrict__ out_b,
    float* __restrict__ out_f)
{
  __shared__ __align__(16) unsigned short As[128 * 32];
  __shared__ __align__(16) unsigned short Bs[128 * 32];
  const int K = 1024;
  int t = threadIdx.x;
  int wv = t >> 6, lane = t & 63;
  int l15 = lane & 15, l4 = lane >> 4;
  int wr = wv >> 1, wc = wv & 1;
  int blkM = blockIdx.y * 128, blkN = blockIdx.x * 128;
  if (MODE == 1) Bt += (size_t)blockIdx.z * SEQ * D_MODEL;

  f32x4 acc[4][4];
  for (int m = 0; m < 4; m++) for (int n = 0; n < 4; n++) acc[m][n] = (f32x4){0.f,0.f,0.f,0.f};

  int srow = t >> 2;
  int skc  = (t & 3) * 8;
  for (int kt = 0; kt < K; kt += 32) {
    #pragma unroll
    for (int i = 0; i < 2; i++) {
      int e = i * 256 + t;
      int row = srow + i * 64;
      gload_lds16(A  + (size_t)(blkM + row) * K + kt + skc, As + e * 8);
      gload_lds16(Bt + (size_t)(blkN + row) * K + kt + skc, Bs + e * 8);
    }
    __syncthreads();
    short8 af[4], bf[4];
    #pragma unroll
    for (int m = 0; m < 4; m++)
      af[m] = *(const short8*)&As[(wr * 64 + m * 16 + l15) * 32 + l4 * 8];
    #pragma unroll
    for (int n = 0; n < 4; n++)
      bf[n] = *(const short8*)&Bs[(wc * 64 + n * 16 + l15) * 32 + l4 * 8];
    #pragma unroll
    for (int m = 0; m < 4; m++)
      #pragma unroll
      for (int n = 0; n < 4; n++)
        acc[m][n] = __builtin_amdgcn_mfma_f32_16x16x32_bf16(af[m], bf[n], acc[m][n], 0, 0, 0);
    __syncthreads();
  }

  int row0 = blkM + wr * 64;
  int col0 = blkN + wc * 64;
  #pragma unroll
  for (int m = 0; m < 4; m++) {
    #pragma unroll
    for (int n = 0; n < 4; n++) {
      int colb = col0 + n * 16 + l15;
      #pragma unroll
      for (int j = 0; j < 4; j++) {
        int row = row0 + m * 16 + l4 * 4 + j;
        float v = acc[m][n][j];
        if (MODE == 0) {
          int s = colb >> 10, hd = colb & 1023;
          v += bias[hd * 3 + s];
          if (s == 0) v *= 0.18033688011112042f;  // (1/8) * log2(e): fold softmax scale + exp2 base
          size_t idx = ((size_t)((row >> 11) * NHEADS + (hd >> 6)) * SEQ + (row & 2047)) * DEPTH + (hd & 63);
          (s == 0 ? out_a : out_b)[idx] = f2bf(v);
        } else if (MODE == 1) {
          v += bias[row * 3 + 2];
          out_a[((size_t)(blockIdx.z * 1024 + row)) * SEQ + colb] = f2bf(v);
        } else {
          v += bias[colb];
          out_f[(size_t)row * D_MODEL + colb] = v;
        }
      }
    }
  }
}

// ---------------- flash attention: 256 q-rows/block, triple-buffer counted-vmcnt ----------------
// Q [32][2048][64] bf16 (pre-scaled 0.125*log2e), K [32][2048][64] bf16, Vt [32][64][2048] bf16
// O  [B][2048][1024] bf16.
//
// 256 blocks (1/CU), 1024 threads = 16 waves. Wave w: qh=w>>1 (32 of 256 q-rows),
// kh=w&1 (32 keys of each staged 64-key tile). K/V re-read traffic drops 4x vs the
// 64-row blocks (512->128 MB aggregate) -- the round-6 wall was L2/L3 staging BW.
// Staging: triple-buffered, prefetch distance 2, ONE gload_lds per thread per iter
// (waves 0-7 stage K, 8-15 stage V). End-of-iter sync is counted `s_waitcnt vmcnt(1)`
// + raw s_barrier: only stage(t+1) must be complete, and it is never the newest of
// the <=2 outstanding loads, so vmcnt(1) is exact; stage(t+2) stays in flight across
// the barrier (no vmcnt(0) drain). Fixed-offset softmax: S acc initialized to -12,
// P=exp2(S'); offset cancels in O=(PV)/(P*1); key-split partials combine linearly.
__global__ __launch_bounds__(1024, 4) void mha_attn(
    const unsigned short* __restrict__ Q,
    const unsigned short* __restrict__ Kb,
    const unsigned short* __restrict__ Vt,
    unsigned short* __restrict__ O)
{
  const int N = SEQ;
  const int NIT = N / 64;                    // 32
  int id = blockIdx.x;                       // 256 blocks
  int bh    = (id & 7) * 4 + ((id >> 6) & 3);  // 4 heads per XCD
  int qtile = (id >> 3) & 7;                 // 8 q-tiles of 256 rows
  int t = threadIdx.x, wv = t >> 6, lane = t & 63;
  int l31 = lane & 31, hi = lane >> 5;
  int qh = wv >> 1, kh = wv & 1;

  __shared__ __align__(16) unsigned short SMEM[3 * 8192];  // 48KB: per buf {K[4096] | V[4096]}
  __shared__ float CMB[8 * 64 * 33];                       // 67.6KB combine scratch

  const unsigned short* Kbh = Kb + (size_t)bh * N * DEPTH;
  const unsigned short* Vbh = Vt + (size_t)bh * DEPTH * N;

  // Q fragments: row q = qrow, depth chunk c: d = c*16 + hi*8 + e
  int qrow = qtile * 256 + qh * 32 + l31;
  const unsigned short* Qp = Q + ((size_t)bh * N + qrow) * DEPTH + hi * 8;
  short8 qf[4];
  #pragma unroll
  for (int c = 0; c < 4; c++) qf[c] = *(const short8*)(Qp + c * 16);

  // staging coords: one 16B granule per thread. threads 0-511: K, 512-1023: V.
  int g   = t & 511;
  int srow = g >> 3;                         // 0..63 (K: key row; V: d row)
  int sc8  = ((g & 7) ^ (srow & 7)) * 8;     // pre-swizzled source column
  bool isK = t < 512;

  // swizzled LDS reads: tile row r, granule gr -> elem r*64 + (gr^(r&7))*8
  int rbK = (kh * 32 + l31) * 64;            // K rows: this wave's 32 keys
  int rbV0 = l31 * 64, rbV1 = rbV0 + 2048;   // V rows: d = l31 / l31+32
  int goQK[4], goPV[2];
  #pragma unroll
  for (int c = 0; c < 4; c++) goQK[c] = ((c * 2 + hi) ^ (l31 & 7)) * 8;
  #pragma unroll
  for (int lc = 0; lc < 2; lc++) goPV[lc] = ((kh * 4 + lc * 2 + hi) ^ (l31 & 7)) * 8;

  f32x16 o0, o1;
  #pragma unroll
  for (int i = 0; i < 16; i++) { o0[i] = 0.f; o1[i] = 0.f; }
  float ls = 0.f;

#define STAGE(buf, kt)                                                                  \
  do {                                                                                  \
    unsigned short* dst = SMEM + (buf) * 8192 + (isK ? 0 : 4096) + g * 8;               \
    if (isK) gload_lds16(Kbh + (size_t)((kt) + srow) * DEPTH + sc8, dst);               \
    else     gload_lds16(Vbh + (size_t)srow * N + (kt) + sc8, dst);                     \
  } while (0)

  // prologue: stage tiles 0,1 into bufs 0,1; ensure buf0 complete (vmcnt(1): the
  // single allowed-outstanding op is stage(1) or a later-sunk Q load; stage(0) done).
  STAGE(0, 0);
  STAGE(1, 64);
  asm volatile("s_waitcnt vmcnt(1)" ::: "memory");
  __builtin_amdgcn_sched_barrier(0);
  __builtin_amdgcn_s_barrier();
  __builtin_amdgcn_sched_barrier(0);

  int cur = 0, sb = 2;                       // compute buf, stage-target buf
  for (int it = 0; it < NIT; ++it) {
    if (it + 2 < NIT) STAGE(sb, (it + 2) * 64);
    const unsigned short* Kc = SMEM + cur * 8192;
    const unsigned short* Vc = Kc + 4096;

    // ---- S^T = mfma(K_half, Q), acc pre-loaded with -12 (softmax offset) ----
    f32x16 s;
    #pragma unroll
    for (int i = 0; i < 16; i++) s[i] = -12.0f;
    __builtin_amdgcn_s_setprio(1);
    #pragma unroll
    for (int c = 0; c < 4; c++) {
      short8 ka = *(const short8*)&Kc[rbK + goQK[c]];
      s = __builtin_amdgcn_mfma_f32_32x32x16_bf16(ka, qf[c], s, 0, 0, 0);
    }
    __builtin_amdgcn_s_setprio(0);

    // ---- P = exp2(S') in-register, accumulate row-sum ----
    float p[16];
    #pragma unroll
    for (int r = 0; r < 16; r++) {
      p[r] = exp2f(s[r]);
      ls += p[r];
    }
    // ---- pack to PV B-fragment (cvt_pk + permlane32_swap), PV ----
    #pragma unroll
    for (int lc = 0; lc < 2; lc++) {
      unsigned int X0 = cvt_pk_bf16(p[8*lc+0], p[8*lc+1]);
      unsigned int X1 = cvt_pk_bf16(p[8*lc+2], p[8*lc+3]);
      unsigned int X2 = cvt_pk_bf16(p[8*lc+4], p[8*lc+5]);
      unsigned int X3 = cvt_pk_bf16(p[8*lc+6], p[8*lc+7]);
      unsigned int W0, W1, W2, W3;
      {
        auto r02 = __builtin_amdgcn_permlane32_swap(X0, X2, false, false);
        auto r13 = __builtin_amdgcn_permlane32_swap(X1, X3, false, false);
        W0 = r02[0]; W2 = r02[1];
        W1 = r13[0]; W3 = r13[1];
      }
      uint4v wvec; wvec[0] = W0; wvec[1] = W1; wvec[2] = W2; wvec[3] = W3;
      short8 bfrag = __builtin_bit_cast(short8, wvec);
      short8 va = *(const short8*)&Vc[rbV0 + goPV[lc]];
      short8 vb = *(const short8*)&Vc[rbV1 + goPV[lc]];
      __builtin_amdgcn_s_setprio(1);
      o0 = __builtin_amdgcn_mfma_f32_32x32x16_bf16(va, bfrag, o0, 0, 0, 0);
      o1 = __builtin_amdgcn_mfma_f32_32x32x16_bf16(vb, bfrag, o1, 0, 0, 0);
      __builtin_amdgcn_s_setprio(0);
    }

    // ---- counted-vmcnt barrier: stage(it+1) done, stage(it+2) stays in flight ----
    if (it < NIT - 1) {
      if (it + 2 < NIT) asm volatile("s_waitcnt vmcnt(1)" ::: "memory");
      else              asm volatile("s_waitcnt vmcnt(0)" ::: "memory");
      __builtin_amdgcn_sched_barrier(0);
      __builtin_amdgcn_s_barrier();
      __builtin_amdgcn_sched_barrier(0);
    }
    cur = (cur == 2) ? 0 : cur + 1;
    sb  = (sb  == 2) ? 0 : sb  + 1;
  }
#undef STAGE

  ls += __shfl_xor(ls, 32);

  // ---- combine key-split partials across wave pairs (same qh, kh 0/1) ----
  if (kh == 1) {
    float* c0 = CMB + (qh * 64 + lane) * 33;
    #pragma unroll
    for (int i = 0; i < 16; i++) { c0[i] = o0[i]; c0[16 + i] = o1[i]; }
    c0[32] = ls;
  }
  __syncthreads();
  if (kh == 0) {
    const float* c0 = CMB + (qh * 64 + lane) * 33;
    #pragma unroll
    for (int i = 0; i < 16; i++) { o0[i] += c0[i]; o1[i] += c0[16 + i]; }
    float rl = 1.0f / (ls + c0[32]);

    int b = bh >> 4, h = bh & 15;
    unsigned short* Op = O + ((size_t)b * N + qrow) * D_MODEL + h * DEPTH;
    // acc layout: col q = l31, row d = (reg&3) + 8*(reg>>2) + 4*hi (+32 for o1)
    #pragma unroll
    for (int gq = 0; gq < 4; gq++) {
      #pragma unroll
      for (int rp = 0; rp < 2; rp++) {
        int reg = gq * 4 + rp * 2;
        int d = gq * 8 + hi * 4 + rp * 2;
        *(unsigned int*)(Op + d)      = cvt_pk_bf16(o0[reg] * rl, o0[reg + 1] * rl);
        *(unsigned int*)(Op + 32 + d) = cvt_pk_bf16(o1[reg] * rl, o1[reg + 1] * rl);
      }
    }
  }
}

extern "C" void kernel_launch(void* const* d_in, const int* in_sizes, int n_in,
                              void* d_out, int out_size, void* d_ws, size_t ws_size,
                              hipStream_t stream) {
  const float* x     = (const float*)d_in[0];
  const float* Wqkv  = (const float*)d_in[1];
  const float* bqkv  = (const float*)d_in[2];
  const float* Wproj = (const float*)d_in[3];
  const float* bproj = (const float*)d_in[4];
  float* out = (float*)d_out;

  char* w = (char*)d_ws;
  unsigned short* xb    = (unsigned short*)(w);                       // 8 MB
  unsigned short* wqkT  = (unsigned short*)(w + 8388608);             // 4 MB
  unsigned short* wvT   = (unsigned short*)(w + 8388608 + 4194304);   // 2 MB
  unsigned short* wpT   = (unsigned short*)(w + 8388608 + 4194304 + 2097152);  // 2 MB
  unsigned short* Qbuf  = (unsigned short*)(w + 16777216);            // 8 MB
  unsigned short* Kbuf  = (unsigned short*)(w + 16777216 + 8388608);  // 8 MB
  unsigned short* Vtb   = (unsigned short*)(w + 16777216 + 16777216); // 8 MB
  unsigned short* AOut  = (unsigned short*)(w + 16777216 + 25165824); // 8 MB

  // 1. x -> bf16
  mha_cvt_bf16<<<M_TOK * D_MODEL / (256 * 8), 256, 0, stream>>>(x, xb);
  // 2. Wqkv -> permuted transposed bf16 (QK part + V part)
  mha_perm_wqkv<<<dim3(96, 32), dim3(32, 8), 0, stream>>>(Wqkv, wqkT, wvT);
  // 3. Wproj -> transposed bf16
  mha_t_wproj<<<dim3(32, 32), dim3(32, 8), 0, stream>>>(Wproj, wpT);
  // 4. QK gemm: [4096 x 2048]
  mha_gemm_bt<0><<<dim3(16, 32), 256, 0, stream>>>(xb, wqkT, bqkv, Qbuf, Kbuf, nullptr);
  // 5. V gemm (transposed output): per batch [1024 x 2048]
  mha_gemm_bt<1><<<dim3(16, 8, 2), 256, 0, stream>>>(wvT, xb, bqkv, Vtb, nullptr, nullptr);
  // 6. flash attention (256 blocks: 1/CU, XCD-local head grouping)
  mha_attn<<<256, 1024, 0, stream>>>(Qbuf, Kbuf, Vtb, AOut);
  // 7. projection gemm -> fp32 out
  mha_gemm_bt<2><<<dim3(8, 32), 256, 0, stream>>>(AOut, wpT, bproj, nullptr, nullptr, out);
}